// Round 17
// baseline (337.894 us; speedup 1.0000x reference)
//
#include <hip/hip_runtime.h>
#include <math.h>

#define GGRP 8
#define NPTS 8192
#define NG   1024      // points per group
#define BB   4
#define FF   64
#define CH   11
#define KF   192       // feature dim F*3
#define NGB  32        // G*B
#define KNN  16

// ws offsets in FLOATS
#define OFF_ORD_E  0        // 8192 int
#define OFF_ORD_A  8192     // 8192 int
#define OFF_BG_E   16384    // 8192 int
#define OFF_BG_A   24576    // 8192 int
#define OFF_MEAN_E 32768    // 96 f
#define OFF_MEAN_A 32896    // 96 f
#define OFF_STD_E  33024    // 2048 f (stores 1/std)
#define OFF_STD_A  35072    // 2048 f
#define OFF_MEANP  37888    // 2*32*64*2*6 = 49152 f (S1x3,S2x3 per (side,gb,f,half))
#define OFF_PART   87040    // 8192*3 f
#define OFF_NORMP  111616   // 6*32*3*1024 = 589824 f
#define OFF_NORMS  701440   // 6*32*1024 = 196608 f
#define OFF_RANK_E 898048   // 8192 int (inverse permutation)
#define OFF_RANK_A 906240   // 8192 int
#define OFF_MAT    1048576
#define MATSZ      6291456  // 32*64*1024*3 floats (P for one side)
#define OFF_BMAT   38797312 // OFF_MAT + 6*MATSZ ; bf16 mats ; D (fp16) overlays OFF_MAT
#define BMAT_FLOATS 18874368
#define FAST_END   57671680 // OFF_BMAT + BMAT_FLOATS
#define OFF_D      38797312 // fallback D region
#define D_FLOATS_PER_GB 1572864   // 3*NG*NG ushorts / 2
// logical matrix order: 0 PE, 1 PA, 2 VE, 3 VA, 4 NPE, 5 NPA

typedef short bf16x8 __attribute__((ext_vector_type(8)));
typedef float f32x4 __attribute__((ext_vector_type(4)));

struct __attribute__((packed, aligned(4))) f4u { float x, y, z, w; };

__device__ __forceinline__ unsigned short f2bf(float v) {
    unsigned u = __builtin_bit_cast(unsigned, v);
    return (unsigned short)((u + 0x7fffu + ((u >> 16) & 1u)) >> 16);   // RNE
}
__device__ __forceinline__ unsigned short f2h(float v) {
    return __builtin_bit_cast(unsigned short, (_Float16)v);            // RNE, monotone
}
__device__ __forceinline__ float h2f(unsigned u16) {
    return (float)__builtin_bit_cast(_Float16, (unsigned short)(u16 & 0xffffu));
}

// one thread per (point, side); channels 3..10 via two align-4 16B loads
__global__ void k_bg(const float* __restrict__ ex, const float* __restrict__ ac, float* ws) {
    int idx = blockIdx.x * blockDim.x + threadIdx.x;
    int n = idx & (NPTS - 1);
    int side = idx >> 13;
    if (idx >= 2 * NPTS) return;
    int* bg = (int*)ws + (side ? OFF_BG_A : OFF_BG_E);
    const float* p = (side ? ac : ex) + (size_t)n * CH + 3;
    f4u a = *(const f4u*)(p);
    f4u b2 = *(const f4u*)(p + 4);
    float v[8] = {a.x, a.y, a.z, a.w, b2.x, b2.y, b2.z, b2.w};
    float m = -1e30f; int am = 0;
#pragma unroll
    for (int c = 0; c < GGRP; c++) { if (v[c] > m) { m = v[c]; am = c; } }
    bg[n] = am;
}

// stable counting-compaction + inverse rank; one block per side, bg staged in LDS
__global__ void k_order(float* ws) {
    int side = blockIdx.x;
    const int* __restrict__ bg = (const int*)ws + (side ? OFF_BG_A : OFF_BG_E);
    int* __restrict__ ord = (int*)ws + (side ? OFF_ORD_A : OFF_ORD_E);
    int* __restrict__ rnk = (int*)ws + (side ? OFF_RANK_A : OFF_RANK_E);
    __shared__ unsigned char bgs[NPTS];
    __shared__ int cnts[8];
    int t = threadIdx.x;
    for (int i = t; i < NPTS; i += 1024) bgs[i] = (unsigned char)bg[i];
    __syncthreads();
    int w = t >> 6, lane = t & 63;
    if (w < 8) {
        int grp = w;
        int cnt = 0;
        for (int base = 0; base < NPTS; base += 64) {
            unsigned long long m = __ballot(bgs[base + lane] == grp);
            cnt += __popcll(m);
        }
        if (lane == 0) cnts[w] = cnt;
    }
    __syncthreads();
    if (w < 8) {
        int grp = w;
        int pos = 0;
        for (int g2 = 0; g2 < grp; g2++) pos += cnts[g2];
        for (int base = 0; base < NPTS; base += 64) {
            int hit = (bgs[base + lane] == grp);
            unsigned long long m = __ballot(hit);
            int pre = __popcll(m & ((1ull << lane) - 1ull));
            if (hit) {
                int slot = pos + pre;
                if (slot < NPTS) { ord[slot] = base + lane; rnk[base + lane] = slot; }
            }
            pos += __popcll(m);
        }
    }
}

// STREAMING gather-by-scatter, POINT-MAJOR P: one block per (f-half, b, side).
__global__ __launch_bounds__(512) void k_gather(const float* __restrict__ ex, const float* __restrict__ ac, float* ws) {
    int fh = blockIdx.x;
    int f = fh >> 1, half = fh & 1;
    int b = blockIdx.y, side = blockIdx.z;
    const int* __restrict__ rnk = (const int*)ws + (side ? OFF_RANK_A : OFF_RANK_E);
    const float4* __restrict__ src4 = (const float4*)((side ? ac : ex) + ((size_t)(b * FF + f) * NPTS) * CH);
    float* __restrict__ P = ws + OFF_MAT + (size_t)side * MATSZ;
    int t = threadIdx.x, w = t >> 6, lane = t & 63;
    float S[8][6];
#pragma unroll
    for (int gg = 0; gg < 8; gg++)
#pragma unroll
        for (int j = 0; j < 6; j++) S[gg][j] = 0.0f;

    float4 v0[2], v2[2], v3[2], v5[2], v6[2], v8[2];
    int4 rk[2];
#pragma unroll
    for (int pass = 0; pass < 2; pass++) {
        int quad = (half * 2 + pass) * 512 + t;   // 4 rows per quad
        const float4* pb = src4 + (size_t)quad * 11;
        v0[pass] = pb[0]; v2[pass] = pb[2]; v3[pass] = pb[3];
        v5[pass] = pb[5]; v6[pass] = pb[6]; v8[pass] = pb[8];
        rk[pass] = *(const int4*)(rnk + quad * 4);
    }
#pragma unroll
    for (int pass = 0; pass < 2; pass++) {
        float xs[4] = {v0[pass].x, v2[pass].w, v5[pass].z, v8[pass].y};
        float ys[4] = {v0[pass].y, v3[pass].x, v5[pass].w, v8[pass].z};
        float zs[4] = {v0[pass].z, v3[pass].y, v6[pass].x, v8[pass].w};
        int rr[4] = {rk[pass].x, rk[pass].y, rk[pass].z, rk[pass].w};
#pragma unroll
        for (int r = 0; r < 4; r++) {
            float x = xs[r], y = ys[r], z = zs[r];
            int g = rr[r] >> 10, pos = rr[r] & 1023;
            size_t mb = (((size_t)(g * 4 + b) * FF + f) * NG + pos) * 3;
            P[mb] = x; P[mb + 1] = y; P[mb + 2] = z;
#pragma unroll
            for (int gg = 0; gg < 8; gg++) {
                float hx = (g == gg) ? x : 0.0f;
                float hy = (g == gg) ? y : 0.0f;
                float hz = (g == gg) ? z : 0.0f;
                S[gg][0] += hx; S[gg][1] += hy; S[gg][2] += hz;
                S[gg][3] += hx * x; S[gg][4] += hy * y; S[gg][5] += hz * z;
            }
        }
    }
    __shared__ float accum[8][8][6];
#pragma unroll
    for (int gg = 0; gg < 8; gg++)
#pragma unroll
        for (int j = 0; j < 6; j++) {
            float s = S[gg][j];
#pragma unroll
            for (int off = 32; off; off >>= 1) s += __shfl_xor(s, off);
            if (lane == 0) accum[w][gg][j] = s;
        }
    __syncthreads();
    if (t < 48) {
        int g = t / 6, j = t % 6;
        float s = 0;
#pragma unroll
        for (int wv = 0; wv < 8; wv++) s += accum[wv][g][j];
        int gb = g * 4 + b;
        ws[OFF_MEANP + (((size_t)(side * NGB + gb) * FF + f) * 2 + half) * 6 + j] = s;
    }
}

// fused mean + 1/std finalize from (S1,S2) partials: one wave per (gb,side)
__global__ void k_statfin(float* ws) {
    int gb = blockIdx.x, side = blockIdx.y;
    int fl = threadIdx.x;   // 0..63 = f
    const float* mp = ws + OFF_MEANP + (((size_t)(side * NGB + gb) * FF + fl) * 2) * 6;
    float s0 = mp[0] + mp[6], s1 = mp[1] + mp[7], s2 = mp[2] + mp[8];
    float q0 = mp[3] + mp[9], q1 = mp[4] + mp[10], q2 = mp[5] + mp[11];
    float t0 = s0, t1 = s1, t2 = s2;
#pragma unroll
    for (int off = 32; off; off >>= 1) {
        t0 += __shfl_xor(t0, off); t1 += __shfl_xor(t1, off); t2 += __shfl_xor(t2, off);
    }
    float m0 = t0 / 65536.0f, m1 = t1 / 65536.0f, m2 = t2 / 65536.0f;
    float sumd = (s0 - 1024.0f * m0) + (s1 - 1024.0f * m1) + (s2 - 1024.0f * m2);
    float sumd2 = (q0 - 2.0f * m0 * s0 + 1024.0f * m0 * m0)
                + (q1 - 2.0f * m1 * s1 + 1024.0f * m1 * m1)
                + (q2 - 2.0f * m2 * s2 + 1024.0f * m2 * m2);
    float var = (sumd2 - sumd * sumd / 3072.0f) / 3071.0f;
    float* st = ws + (side ? OFF_STD_A : OFF_STD_E);
    st[gb * FF + fl] = 1.0f / sqrtf(fmaxf(var, 0.0f));
    if (fl == 0) {
        float* m = ws + (side ? OFF_MEAN_A : OFF_MEAN_E) + gb * 3;
        m[0] = m0; m[1] = m1; m[2] = m2;
    }
}

// transpose point-major P [f][pos][3] -> THREE bf16 mats [i][k] (P, V, NP)
__global__ void k_tobf3(float* ws) {
    int x = blockIdx.x;
    int it = x & 15, kt = x >> 4;
    int gb = blockIdx.y, side = blockIdx.z;
    int k0 = kt * 64, i0 = it * 64;
    int fstart = (k0 >= 3) ? (k0 - 3) / 3 : 0;
    int fend = (k0 + 63) / 3;
    int nf = fend - fstart + 1;     // 22/23/23
    const float* __restrict__ Pb = ws + OFF_MAT + (size_t)side * MATSZ + ((size_t)gb * FF) * NG * 3;
    unsigned short* bm = (unsigned short*)(ws + OFF_BMAT);
    const float* mean = ws + (side ? OFF_MEAN_A : OFF_MEAN_E) + gb * 3;
    const float* rst = ws + (side ? OFF_STD_A : OFF_STD_E) + gb * FF;
    float m0 = mean[0], m1 = mean[1], m2 = mean[2];
    __shared__ float tile[69][65];   // rows = krow = k - 3*fstart
    int t = threadIdx.x;
    int ii = t & 63, fq = t >> 6;
#pragma unroll
    for (int pass = 0; pass < 6; pass++) {
        int fl = pass * 4 + fq;
        if (fl < nf) {
            const float* p = Pb + (((size_t)(fstart + fl) * NG) + i0 + ii) * 3;
            tile[fl * 3 + 0][ii] = p[0];
            tile[fl * 3 + 1][ii] = p[1];
            tile[fl * 3 + 2][ii] = p[2];
        }
    }
    __syncthreads();
    int kk2 = t & 63, iq = t >> 6;
    int k = k0 + kk2;
    int c = k % 3, f = k / 3;
    int krow = k - fstart * 3;
    float mm = (c == 0) ? m0 : ((c == 1) ? m1 : m2);
    float rs = rst[f];
    size_t moff = ((size_t)side * NGB + gb) * (size_t)(NG * KF);
    size_t voff = ((size_t)(2 + side) * NGB + gb) * (size_t)(NG * KF);
    size_t noff = ((size_t)(4 + side) * NGB + gb) * (size_t)(NG * KF);
    float* npP = ws + OFF_NORMP + ((size_t)(side * NGB + gb) * 3 + kt) * NG;
    float* npV = ws + OFF_NORMP + ((size_t)((2 + side) * NGB + gb) * 3 + kt) * NG;
    float* npN = ws + OFF_NORMP + ((size_t)((4 + side) * NGB + gb) * 3 + kt) * NG;
#pragma unroll
    for (int rep = 0; rep < 16; rep++) {
        int i2 = iq + rep * 4;
        float p = tile[krow][i2];
        float vV = (k >= 3) ? (p - tile[krow - 3][i2]) : 0.0f;
        float vN = (p - mm) * rs;
        size_t ob = (size_t)(i0 + i2) * KF + k;
        bm[moff + ob] = f2bf(p);
        bm[voff + ob] = f2bf(vV);
        bm[noff + ob] = f2bf(vN);
        float nP = p * p, nV = vV * vV, nN = vN * vN;
#pragma unroll
        for (int off = 32; off; off >>= 1) {
            nP += __shfl_xor(nP, off); nV += __shfl_xor(nV, off); nN += __shfl_xor(nN, off);
        }
        if (kk2 == 0) { npP[i0 + i2] = nP; npV[i0 + i2] = nV; npN[i0 + i2] = nN; }
    }
}

__global__ void k_normfin(float* ws) {
    int mat = blockIdx.x, gb = blockIdx.y;
    const float* np = ws + OFF_NORMP + (size_t)(mat * NGB + gb) * 3 * NG;
    float* nr = ws + OFF_NORMS + ((size_t)mat * NGB + gb) * NG;
    for (int i = threadIdx.x; i < NG; i += 256)
        nr[i] = np[i] + np[NG + i] + np[2 * NG + i];
}

// MFMA distance GEMM: 128x128 tile, 4 waves (2x2), BK=64, swizzled LDS.
// Epilogue stages fp16 D tile in LDS (stride 132) then copies out with
// coalesced uint2 stores (16x 8B per thread instead of 64x 2B scalar).
#define LDSTR 132
__global__ __launch_bounds__(256) void k_mgemm(float* ws, int cs, unsigned long long dOff) {
    int bx = blockIdx.x, by = blockIdx.y;
    int bz = blockIdx.z; int gbl = bz / 3, m3 = bz % 3;
    int gb = cs + gbl;
    int eIdx = (m3 == 0) ? 0 : ((m3 == 1) ? 4 : 2);
    int aIdx = (m3 == 0) ? 1 : ((m3 == 1) ? 5 : 3);
    const unsigned short* bmat = (const unsigned short*)(ws + OFF_BMAT);
    const unsigned short* Eg = bmat + ((size_t)eIdx * NGB + gb) * (size_t)(NG * KF);
    const unsigned short* Ag = bmat + ((size_t)aIdx * NGB + gb) * (size_t)(NG * KF);
    const float* rnE = ws + OFF_NORMS + ((size_t)eIdx * NGB + gb) * NG;
    const float* cnA = ws + OFF_NORMS + ((size_t)aIdx * NGB + gb) * NG;
    unsigned short* D = (unsigned short*)(ws + dOff) + ((size_t)gbl * 3 + m3) * (size_t)(NG * NG);
    int i0 = by * 128, j0 = bx * 128;
    __shared__ __align__(16) unsigned short lsh[128 * LDSTR];   // 33792 B; staging uses first 32768 B
    unsigned short* lE = lsh;
    unsigned short* lA = lsh + 128 * 64;
    int tid = threadIdx.x;
    int wid = tid >> 6, lane = tid & 63;
    int wr = wid >> 1, wc = wid & 1;
    f32x4 acc[4][4];
#pragma unroll
    for (int m = 0; m < 4; m++)
#pragma unroll
        for (int n = 0; n < 4; n++) acc[m][n] = (f32x4){0.f, 0.f, 0.f, 0.f};

    int rr = lane >> 3, ss = lane & 7;
    for (int k0 = 0; k0 < KF; k0 += 64) {
        if (k0) __syncthreads();
#pragma unroll
        for (int q = 0; q < 4; q++) {
            int r0 = wid * 32 + q * 8;
            int r = r0 + rr;
            int c = ss ^ (r & 7);
            __builtin_amdgcn_global_load_lds(
                (const __attribute__((address_space(1))) void*)(Eg + (size_t)(i0 + r) * KF + k0 + c * 8),
                (__attribute__((address_space(3))) void*)&lE[r0 * 64], 16, 0, 0);
            __builtin_amdgcn_global_load_lds(
                (const __attribute__((address_space(1))) void*)(Ag + (size_t)(j0 + r) * KF + k0 + c * 8),
                (__attribute__((address_space(3))) void*)&lA[r0 * 64], 16, 0, 0);
        }
        asm volatile("s_waitcnt vmcnt(0)" ::: "memory");
        __syncthreads();
#pragma unroll
        for (int ks = 0; ks < 2; ks++) {
            bf16x8 af[4], bfr[4];
            int kb = ks * 64 + (lane >> 4) * 16;
#pragma unroll
            for (int m = 0; m < 4; m++) {
                int arow = wr * 64 + m * 16 + (lane & 15);
                af[m] = *(const bf16x8*)((const char*)lE + arow * 128 + (kb ^ ((arow & 7) << 4)));
            }
#pragma unroll
            for (int n = 0; n < 4; n++) {
                int brow = wc * 64 + n * 16 + (lane & 15);
                bfr[n] = *(const bf16x8*)((const char*)lA + brow * 128 + (kb ^ ((brow & 7) << 4)));
            }
#pragma unroll
            for (int m = 0; m < 4; m++)
#pragma unroll
                for (int n = 0; n < 4; n++)
                    acc[m][n] = __builtin_amdgcn_mfma_f32_16x16x32_bf16(af[m], bfr[n], acc[m][n], 0, 0, 0);
        }
    }

    int colbase = j0 + wc * 64 + (lane & 15);
    int rowbase = i0 + wr * 64 + ((lane >> 4) << 2);
    float cn[4];
#pragma unroll
    for (int n = 0; n < 4; n++) cn[n] = cnA[colbase + n * 16];

    __syncthreads();   // staging dead; reuse lsh as D tile [128][LDSTR]
    int lcolb = wc * 64 + (lane & 15);
    int lrowb = wr * 64 + ((lane >> 4) << 2);
#pragma unroll
    for (int m = 0; m < 4; m++) {
        int rb = rowbase + m * 16;
        int lrb = lrowb + m * 16;
#pragma unroll
        for (int r = 0; r < 4; r++) {
            float rn = rnE[rb + r];
#pragma unroll
            for (int n = 0; n < 4; n++) {
                float d = rn + cn[n] - 2.0f * acc[m][n][r];
                lsh[(size_t)(lrb + r) * LDSTR + lcolb + n * 16] = f2h(fmaxf(d, 1e-12f));
            }
        }
    }
    __syncthreads();
    // copy out: thread t -> row t>>1, half t&1 (64 ushorts = 16x uint2)
    {
        int row = tid >> 1, hf = tid & 1;
        const unsigned short* src = lsh + (size_t)row * LDSTR + hf * 64;
        unsigned short* dst = D + (size_t)(i0 + row) * NG + j0 + hf * 64;
#pragma unroll
        for (int k = 0; k < 16; k++) {
            *(uint2*)(dst + k * 4) = *(const uint2*)(src + k * 4);
        }
    }
}

// ---- fallback path (small ws): column-major gather + fp32 derive/norms/gemm ----
__global__ __launch_bounds__(512) void k_gather_cols(const float* __restrict__ ex, const float* __restrict__ ac, float* ws) {
    int fh = blockIdx.x;
    int f = fh >> 1, half = fh & 1;
    int b = blockIdx.y, side = blockIdx.z;
    const int* __restrict__ rnk = (const int*)ws + (side ? OFF_RANK_A : OFF_RANK_E);
    const float4* __restrict__ src4 = (const float4*)((side ? ac : ex) + ((size_t)(b * FF + f) * NPTS) * CH);
    float* __restrict__ P = ws + OFF_MAT + (size_t)side * MATSZ;
    int t = threadIdx.x, w = t >> 6, lane = t & 63;
    float S[8][6];
#pragma unroll
    for (int gg = 0; gg < 8; gg++)
#pragma unroll
        for (int j = 0; j < 6; j++) S[gg][j] = 0.0f;
#pragma unroll
    for (int pass = 0; pass < 2; pass++) {
        int quad = (half * 2 + pass) * 512 + t;
        int n0 = quad * 4;
        const float4* pb = src4 + (size_t)quad * 11;
        float4 v0 = pb[0], v2 = pb[2], v3 = pb[3], v5 = pb[5], v6 = pb[6], v8 = pb[8];
        int4 rk = *(const int4*)(rnk + n0);
        float xs[4] = {v0.x, v2.w, v5.z, v8.y};
        float ys[4] = {v0.y, v3.x, v5.w, v8.z};
        float zs[4] = {v0.z, v3.y, v6.x, v8.w};
        int rr[4] = {rk.x, rk.y, rk.z, rk.w};
#pragma unroll
        for (int r = 0; r < 4; r++) {
            float x = xs[r], y = ys[r], z = zs[r];
            int g = rr[r] >> 10, pos = rr[r] & 1023;
            size_t mb = ((size_t)((g * 4 + b) * KF + f * 3)) * NG + pos;
            P[mb] = x; P[mb + NG] = y; P[mb + 2 * NG] = z;
#pragma unroll
            for (int gg = 0; gg < 8; gg++) {
                float hx = (g == gg) ? x : 0.0f;
                float hy = (g == gg) ? y : 0.0f;
                float hz = (g == gg) ? z : 0.0f;
                S[gg][0] += hx; S[gg][1] += hy; S[gg][2] += hz;
                S[gg][3] += hx * x; S[gg][4] += hy * y; S[gg][5] += hz * z;
            }
        }
    }
    __shared__ float accum[8][8][6];
#pragma unroll
    for (int gg = 0; gg < 8; gg++)
#pragma unroll
        for (int j = 0; j < 6; j++) {
            float s = S[gg][j];
#pragma unroll
            for (int off = 32; off; off >>= 1) s += __shfl_xor(s, off);
            if (lane == 0) accum[w][gg][j] = s;
        }
    __syncthreads();
    if (t < 48) {
        int g = t / 6, j = t % 6;
        float s = 0;
#pragma unroll
        for (int wv = 0; wv < 8; wv++) s += accum[wv][g][j];
        int gb = g * 4 + b;
        ws[OFF_MEANP + (((size_t)(side * NGB + gb) * FF + f) * 2 + half) * 6 + j] = s;
    }
}

__global__ void k_derive(float* ws) {
    int k = blockIdx.x, gb = blockIdx.y;
    int f = k / 3, c = k % 3;
    for (int side = 0; side < 2; side++) {
        const float* P = ws + OFF_MAT + (size_t)side * MATSZ;
        float* V = ws + OFF_MAT + (size_t)(2 + side) * MATSZ;
        float* NP = ws + OFF_MAT + (size_t)(4 + side) * MATSZ;
        const float* mean = ws + (side ? OFF_MEAN_A : OFF_MEAN_E) + gb * 3;
        const float* rst = ws + (side ? OFF_STD_A : OFF_STD_E) + gb * FF;
        float mm = mean[c];
        float rs = rst[f];
        size_t base = ((size_t)gb * KF + k) * NG;
        for (int i = threadIdx.x; i < NG; i += 256) {
            float p = P[base + i];
            V[base + i] = f ? (p - P[base - 3 * NG + i]) : 0.0f;
            NP[base + i] = (p - mm) * rs;
        }
    }
}

__global__ void k_norms(float* ws) {
    int mat = blockIdx.x, gb = blockIdx.y;
    const float* M = ws + OFF_MAT + (size_t)mat * MATSZ + (size_t)gb * KF * NG;
    float* nr = ws + OFF_NORMS + ((size_t)mat * NGB + gb) * NG;
    for (int i = threadIdx.x; i < NG; i += 256) {
        float s = 0;
        for (int k = 0; k < KF; k++) { float v = M[(size_t)k * NG + i]; s += v * v; }
        nr[i] = s;
    }
}

__global__ __launch_bounds__(256) void k_gemm(float* ws, int cs) {
    int bx = blockIdx.x, by = blockIdx.y;
    int bz = blockIdx.z; int gbl = bz / 3, m = bz % 3;
    int gb = cs + gbl;
    int eIdx = (m == 0) ? 0 : ((m == 1) ? 4 : 2);
    int aIdx = (m == 0) ? 1 : ((m == 1) ? 5 : 3);
    const float* E = ws + OFF_MAT + (size_t)eIdx * MATSZ + (size_t)gb * KF * NG;
    const float* A = ws + OFF_MAT + (size_t)aIdx * MATSZ + (size_t)gb * KF * NG;
    const float* rnE = ws + OFF_NORMS + ((size_t)eIdx * NGB + gb) * NG;
    const float* cnA = ws + OFF_NORMS + ((size_t)aIdx * NGB + gb) * NG;
    unsigned short* D = (unsigned short*)(ws + OFF_D) + ((size_t)gbl * 3 + m) * (size_t)(NG * NG);
    int i0 = by * 128, j0 = bx * 128;
    __shared__ float4 Et[8][32], At[8][32];
    int tx = threadIdx.x, ty = threadIdx.y;
    int tid = ty * 16 + tx;
    float acc[2][2][4][4] = {};
    for (int k0 = 0; k0 < KF; k0 += 8) {
        {
            int kk = tid >> 5, i4 = tid & 31;
            Et[kk][i4] = *(const float4*)&E[(size_t)(k0 + kk) * NG + i0 + i4 * 4];
            At[kk][i4] = *(const float4*)&A[(size_t)(k0 + kk) * NG + j0 + i4 * 4];
        }
        __syncthreads();
#pragma unroll
        for (int kk = 0; kk < 8; kk++) {
            float4 e0 = Et[kk][ty], e1 = Et[kk][16 + ty];
            float4 a0 = At[kk][tx], a1 = At[kk][16 + tx];
            float er[2][4] = {{e0.x, e0.y, e0.z, e0.w}, {e1.x, e1.y, e1.z, e1.w}};
            float ar[2][4] = {{a0.x, a0.y, a0.z, a0.w}, {a1.x, a1.y, a1.z, a1.w}};
#pragma unroll
            for (int p = 0; p < 2; p++)
#pragma unroll
                for (int q = 0; q < 2; q++)
#pragma unroll
                    for (int r = 0; r < 4; r++)
#pragma unroll
                        for (int cc = 0; cc < 4; cc++)
                            acc[p][q][r][cc] += er[p][r] * ar[q][cc];
        }
        __syncthreads();
    }
    float rn[2][4], cn[2][4];
#pragma unroll
    for (int p = 0; p < 2; p++)
#pragma unroll
        for (int r = 0; r < 4; r++) rn[p][r] = rnE[i0 + p * 64 + ty * 4 + r];
#pragma unroll
    for (int q = 0; q < 2; q++)
#pragma unroll
        for (int cc = 0; cc < 4; cc++) cn[q][cc] = cnA[j0 + q * 64 + tx * 4 + cc];
#pragma unroll
    for (int p = 0; p < 2; p++)
#pragma unroll
        for (int r = 0; r < 4; r++) {
            int gi = i0 + p * 64 + ty * 4 + r;
#pragma unroll
            for (int q = 0; q < 2; q++)
#pragma unroll
                for (int cc = 0; cc < 4; cc++) {
                    float d = fmaxf(rn[p][r] + cn[q][cc] - 2.0f * acc[p][q][r][cc], 1e-12f);
                    D[(size_t)gi * NG + j0 + q * 64 + tx * 4 + cc] = f2h(d);
                }
        }
}

// ---------------------------------------------------------------------------
// per-row top-16 on FP16 squared distances via bound -> compact -> bitonic.
// Loads: 2x uint4 per list per lane. value slot vq (0..15):
//   col = (vq<8) ? 8*lane + vq : 512 + 8*lane + (vq-8)
// ---------------------------------------------------------------------------
__global__ void k_select(float* ws, int cs, unsigned long long dOff) {
    int gbl = blockIdx.y; int gb = cs + gbl;
    int w = threadIdx.x >> 6, lane = threadIdx.x & 63;
    int row = blockIdx.x * 4 + w;
    const unsigned short* Db = (const unsigned short*)(ws + dOff) + (size_t)gbl * 3 * (size_t)(NG * NG);
    const uint4* dg4 = (const uint4*)(Db + (size_t)row * NG);
    const uint4* dn4 = (const uint4*)(Db + (size_t)(NG * NG) + (size_t)row * NG);
    const uint4* dv4 = (const uint4*)(Db + (size_t)2 * (NG * NG) + (size_t)row * NG);
    uint4 ga = dg4[lane], gbq = dg4[64 + lane];
    uint4 na = dn4[lane], nb = dn4[64 + lane];
    uint4 va = dv4[lane], vb = dv4[64 + lane];
    unsigned ug[8] = {ga.x, ga.y, ga.z, ga.w, gbq.x, gbq.y, gbq.z, gbq.w};
    unsigned un[8] = {na.x, na.y, na.z, na.w, nb.x, nb.y, nb.z, nb.w};
    unsigned uv[8] = {va.x, va.y, va.z, va.w, vb.x, vb.y, vb.z, vb.w};
    float dgv[16], dnv[16], dvv[16];
#pragma unroll
    for (int q = 0; q < 8; q++) {
        dgv[2 * q] = h2f(ug[q]); dgv[2 * q + 1] = h2f(ug[q] >> 16);
        dnv[2 * q] = h2f(un[q]); dnv[2 * q + 1] = h2f(un[q] >> 16);
        dvv[2 * q] = h2f(uv[q]); dvv[2 * q + 1] = h2f(uv[q] >> 16);
    }
    __shared__ float sKey[4][64];
    __shared__ float sPay[4][64];
    __shared__ int   sCol[4][64];
    unsigned long long ltm = (1ull << lane) - 1ull;
    float sg = 0, sv = 0, sn = 0;
    int colb = lane * 8;

    // ============ list A: dg (payload dv, tie-break col) ============
    {
        float lm = dgv[0];
#pragma unroll
        for (int q = 1; q < 16; q++) lm = fminf(lm, dgv[q]);
#pragma unroll
        for (int k2 = 2; k2 <= 64; k2 <<= 1)
#pragma unroll
            for (int j = k2 >> 1; j; j >>= 1) {
                float o = __shfl_xor(lm, j);
                bool takeMin = (((lane & j) == 0) == ((lane & k2) == 0));
                lm = takeMin ? fminf(lm, o) : fmaxf(lm, o);
            }
        float tau = __shfl(lm, 15);
        int cnt = 0;
#pragma unroll
        for (int q = 0; q < 16; q++) cnt += (int)__popcll(__ballot(dgv[q] <= tau));
        if (cnt <= 64) {
            int base = 0;
#pragma unroll
            for (int vq = 0; vq < 16; vq++) {
                bool c = (dgv[vq] <= tau);
                unsigned long long bal = __ballot(c);
                if (c) {
                    int slot = base + (int)__popcll(bal & ltm);
                    sKey[w][slot] = dgv[vq]; sPay[w][slot] = dvv[vq];
                    sCol[w][slot] = (vq < 8) ? (colb + vq) : (512 + colb + vq - 8);
                }
                base += (int)__popcll(bal);
            }
            asm volatile("s_waitcnt lgkmcnt(0)" ::: "memory");
            float key = (lane < cnt) ? sKey[w][lane] : 3.4e38f;
            float pay = (lane < cnt) ? sPay[w][lane] : 0.0f;
            int   col = (lane < cnt) ? sCol[w][lane] : 0x7fffffff;
#pragma unroll
            for (int k2 = 2; k2 <= 64; k2 <<= 1)
#pragma unroll
                for (int j = k2 >> 1; j; j >>= 1) {
                    float ok = __shfl_xor(key, j);
                    float op = __shfl_xor(pay, j);
                    int   oc = __shfl_xor(col, j);
                    bool mineSmaller = (key < ok) || (key == ok && col < oc);
                    bool wantSmall = (((lane & j) == 0) == ((lane & k2) == 0));
                    if (mineSmaller != wantSmall) { key = ok; pay = op; col = oc; }
                }
            float a = (lane < 16) ? sqrtf(key) : 0.0f;
            float b = (lane < 16) ? sqrtf(pay) : 0.0f;
#pragma unroll
            for (int off = 32; off; off >>= 1) { a += __shfl_xor(a, off); b += __shfl_xor(b, off); }
            sg = a; sv = b;
        } else {
            for (int it = 0; it < KNN; it++) {
                float best = 3.4e38f; int bc = 0x7fffffff;
#pragma unroll
                for (int vq = 0; vq < 16; vq++) {
                    float v = dgv[vq];
                    int c = (vq < 8) ? (colb + vq) : (512 + colb + vq - 8);
                    if (v < best) { best = v; bc = c; }
                }
#pragma unroll
                for (int off = 32; off; off >>= 1) {
                    float ov = __shfl_xor(best, off); int oc = __shfl_xor(bc, off);
                    if (ov < best || (ov == best && oc < bc)) { best = ov; bc = oc; }
                }
                sg += sqrtf(best);
                int bl = ((bc & 511) >> 3);
                int bq = (bc & 7) + ((bc >= 512) ? 8 : 0);
                float t = 0;
#pragma unroll
                for (int vq = 0; vq < 16; vq++) if (vq == bq) t = dvv[vq];
                t = __shfl(t, bl); sv += sqrtf(t);
                if (lane == bl) {
#pragma unroll
                    for (int vq = 0; vq < 16; vq++) if (vq == bq) dgv[vq] = 3.4e38f;
                }
            }
        }
    }

    // ============ list B: dn (values only) ============
    {
        float lm = dnv[0];
#pragma unroll
        for (int q = 1; q < 16; q++) lm = fminf(lm, dnv[q]);
#pragma unroll
        for (int k2 = 2; k2 <= 64; k2 <<= 1)
#pragma unroll
            for (int j = k2 >> 1; j; j >>= 1) {
                float o = __shfl_xor(lm, j);
                bool takeMin = (((lane & j) == 0) == ((lane & k2) == 0));
                lm = takeMin ? fminf(lm, o) : fmaxf(lm, o);
            }
        float tau = __shfl(lm, 15);
        int cnt = 0;
#pragma unroll
        for (int q = 0; q < 16; q++) cnt += (int)__popcll(__ballot(dnv[q] <= tau));
        if (cnt <= 64) {
            int base = 0;
#pragma unroll
            for (int vq = 0; vq < 16; vq++) {
                bool c = (dnv[vq] <= tau);
                unsigned long long bal = __ballot(c);
                if (c) {
                    int slot = base + (int)__popcll(bal & ltm);
                    sKey[w][slot] = dnv[vq];
                }
                base += (int)__popcll(bal);
            }
            asm volatile("s_waitcnt lgkmcnt(0)" ::: "memory");
            float key = (lane < cnt) ? sKey[w][lane] : 3.4e38f;
#pragma unroll
            for (int k2 = 2; k2 <= 64; k2 <<= 1)
#pragma unroll
                for (int j = k2 >> 1; j; j >>= 1) {
                    float o = __shfl_xor(key, j);
                    bool takeMin = (((lane & j) == 0) == ((lane & k2) == 0));
                    key = takeMin ? fminf(key, o) : fmaxf(key, o);
                }
            float a = (lane < 16) ? sqrtf(key) : 0.0f;
#pragma unroll
            for (int off = 32; off; off >>= 1) a += __shfl_xor(a, off);
            sn = a;
        } else {
            for (int it = 0; it < KNN; it++) {
                float best = 3.4e38f; int bc = 0x7fffffff;
#pragma unroll
                for (int vq = 0; vq < 16; vq++) {
                    float v = dnv[vq];
                    int c = (vq < 8) ? (colb + vq) : (512 + colb + vq - 8);
                    if (v < best) { best = v; bc = c; }
                }
#pragma unroll
                for (int off = 32; off; off >>= 1) {
                    float ov = __shfl_xor(best, off); int oc = __shfl_xor(bc, off);
                    if (ov < best || (ov == best && oc < bc)) { best = ov; bc = oc; }
                }
                sn += sqrtf(best);
                int bl = ((bc & 511) >> 3);
                int bq = (bc & 7) + ((bc >= 512) ? 8 : 0);
                if (lane == bl) {
#pragma unroll
                    for (int vq = 0; vq < 16; vq++) if (vq == bq) dnv[vq] = 3.4e38f;
                }
            }
        }
    }

    __shared__ float ssum[4][3];
    if (lane == 0) { ssum[w][0] = sg; ssum[w][1] = sn; ssum[w][2] = sv; }
    __syncthreads();
    if (threadIdx.x == 0) {
        float* part = ws + OFF_PART + ((size_t)gb * 256 + blockIdx.x) * 3;
        part[0] = ssum[0][0] + ssum[1][0] + ssum[2][0] + ssum[3][0];
        part[1] = ssum[0][1] + ssum[1][1] + ssum[2][1] + ssum[3][1];
        part[2] = ssum[0][2] + ssum[1][2] + ssum[2][2] + ssum[3][2];
    }
}

__global__ void k_reduce(float* ws, float* out, int n) {
    double s[3] = {0, 0, 0};
    for (int idx = threadIdx.x; idx < n; idx += 256) {
        const float* p = ws + OFF_PART + (size_t)idx * 3;
        s[0] += p[0]; s[1] += p[1]; s[2] += p[2];
    }
    __shared__ double red[256];
    for (int m = 0; m < 3; m++) {
        red[threadIdx.x] = s[m]; __syncthreads();
        for (int off = 128; off; off >>= 1) { if (threadIdx.x < off) red[threadIdx.x] += red[threadIdx.x + off]; __syncthreads(); }
        if (threadIdx.x == 0) out[m] = (float)(red[0] / 524288.0 / 8.0);
        __syncthreads();
    }
}

extern "C" void kernel_launch(void* const* d_in, const int* in_sizes, int n_in,
                              void* d_out, int out_size, void* d_ws, size_t ws_size,
                              hipStream_t stream) {
    const float* ex = (const float*)d_in[0];
    const float* ac = (const float*)d_in[1];
    float* ws = (float*)d_ws;
    float* out = (float*)d_out;

    hipLaunchKernelGGL(k_bg, dim3(64), dim3(256), 0, stream, ex, ac, ws);
    hipLaunchKernelGGL(k_order, dim3(2), dim3(1024), 0, stream, ws);

    size_t ws_floats = ws_size / 4;
    bool fast = ws_floats >= (size_t)FAST_END;

    if (fast) {
        hipLaunchKernelGGL(k_gather, dim3(128, BB, 2), dim3(512), 0, stream, ex, ac, ws);
        hipLaunchKernelGGL(k_statfin, dim3(NGB, 2), dim3(64), 0, stream, ws);
        hipLaunchKernelGGL(k_tobf3, dim3(48, NGB, 2), dim3(256), 0, stream, ws);
        hipLaunchKernelGGL(k_normfin, dim3(6, NGB), dim3(256), 0, stream, ws);
        int gbc = 16;  // fp16 D overlays the dead fp32 P region after k_tobf3
        for (int cs = 0; cs < NGB; cs += gbc) {
            int take = (NGB - cs < gbc) ? (NGB - cs) : gbc;
            hipLaunchKernelGGL(k_mgemm, dim3(8, 8, take * 3), dim3(256), 0, stream, ws, cs, (unsigned long long)OFF_MAT);
            hipLaunchKernelGGL(k_select, dim3(256, take), dim3(256), 0, stream, ws, cs, (unsigned long long)OFF_MAT);
        }
        hipLaunchKernelGGL(k_reduce, dim3(1), dim3(256), 0, stream, ws, out, 8192);
    } else {
        hipLaunchKernelGGL(k_gather_cols, dim3(128, BB, 2), dim3(512), 0, stream, ex, ac, ws);
        hipLaunchKernelGGL(k_statfin, dim3(NGB, 2), dim3(64), 0, stream, ws);
        hipLaunchKernelGGL(k_derive, dim3(KF, NGB), dim3(256), 0, stream, ws);
        hipLaunchKernelGGL(k_norms, dim3(6, NGB), dim3(256), 0, stream, ws);
        size_t dcap = (ws_floats > (size_t)OFF_D) ? (ws_floats - (size_t)OFF_D) : 0;
        int gbc = (int)(dcap / (size_t)D_FLOATS_PER_GB);
        if (gbc < 1) gbc = 1;
        if (gbc > 32) gbc = 32;
        for (int cs = 0; cs < NGB; cs += gbc) {
            int take = (NGB - cs < gbc) ? (NGB - cs) : gbc;
            hipLaunchKernelGGL(k_gemm, dim3(8, 8, take * 3), dim3(16, 16), 0, stream, ws, cs);
            hipLaunchKernelGGL(k_select, dim3(256, take), dim3(256), 0, stream, ws, cs, (unsigned long long)OFF_D);
        }
        hipLaunchKernelGGL(k_reduce, dim3(1), dim3(256), 0, stream, ws, out, 8192);
    }
}

// Round 18
// 313.790 us; speedup vs baseline: 1.0768x; 1.0768x over previous
//
#include <hip/hip_runtime.h>
#include <math.h>

#define GGRP 8
#define NPTS 8192
#define NG   1024      // points per group
#define BB   4
#define FF   64
#define CH   11
#define KF   192       // feature dim F*3
#define NGB  32        // G*B
#define KNN  16

// ws offsets in FLOATS
#define OFF_ORD_E  0        // 8192 int
#define OFF_ORD_A  8192     // 8192 int
#define OFF_BG_E   16384    // 8192 int
#define OFF_BG_A   24576    // 8192 int
#define OFF_MEAN_E 32768    // 96 f
#define OFF_MEAN_A 32896    // 96 f
#define OFF_STD_E  33024    // 2048 f (stores 1/std)
#define OFF_STD_A  35072    // 2048 f
#define OFF_MEANP  37888    // 2*32*64*2*6 = 49152 f (S1x3,S2x3 per (side,gb,f,half))
#define OFF_PART   87040    // 8192*3 f
#define OFF_NORMP  111616   // 6*32*3*1024 = 589824 f
#define OFF_NORMS  701440   // 6*32*1024 = 196608 f
#define OFF_RANK_E 898048   // 8192 int (inverse permutation)
#define OFF_RANK_A 906240   // 8192 int
#define OFF_MAT    1048576
#define MATSZ      6291456  // 32*64*1024*3 floats (P for one side)
#define OFF_BMAT   38797312 // OFF_MAT + 6*MATSZ ; bf16 mats ; D (fp16) overlays OFF_MAT
#define BMAT_FLOATS 18874368
#define FAST_END   57671680 // OFF_BMAT + BMAT_FLOATS
#define OFF_D      38797312 // fallback D region
#define D_FLOATS_PER_GB 1572864   // 3*NG*NG ushorts / 2
// logical matrix order: 0 PE, 1 PA, 2 VE, 3 VA, 4 NPE, 5 NPA

typedef short bf16x8 __attribute__((ext_vector_type(8)));
typedef float f32x4 __attribute__((ext_vector_type(4)));

struct __attribute__((packed, aligned(4))) f4u { float x, y, z, w; };

__device__ __forceinline__ unsigned short f2bf(float v) {
    unsigned u = __builtin_bit_cast(unsigned, v);
    return (unsigned short)((u + 0x7fffu + ((u >> 16) & 1u)) >> 16);   // RNE
}
__device__ __forceinline__ unsigned short f2h(float v) {
    return __builtin_bit_cast(unsigned short, (_Float16)v);            // RNE, monotone
}
__device__ __forceinline__ float h2f(unsigned u16) {
    return (float)__builtin_bit_cast(_Float16, (unsigned short)(u16 & 0xffffu));
}

// one thread per (point, side); channels 3..10 via two align-4 16B loads
__global__ void k_bg(const float* __restrict__ ex, const float* __restrict__ ac, float* ws) {
    int idx = blockIdx.x * blockDim.x + threadIdx.x;
    int n = idx & (NPTS - 1);
    int side = idx >> 13;
    if (idx >= 2 * NPTS) return;
    int* bg = (int*)ws + (side ? OFF_BG_A : OFF_BG_E);
    const float* p = (side ? ac : ex) + (size_t)n * CH + 3;
    f4u a = *(const f4u*)(p);
    f4u b2 = *(const f4u*)(p + 4);
    float v[8] = {a.x, a.y, a.z, a.w, b2.x, b2.y, b2.z, b2.w};
    float m = -1e30f; int am = 0;
#pragma unroll
    for (int c = 0; c < GGRP; c++) { if (v[c] > m) { m = v[c]; am = c; } }
    bg[n] = am;
}

// stable counting-compaction + inverse rank; one block per side, bg staged in LDS
__global__ void k_order(float* ws) {
    int side = blockIdx.x;
    const int* __restrict__ bg = (const int*)ws + (side ? OFF_BG_A : OFF_BG_E);
    int* __restrict__ ord = (int*)ws + (side ? OFF_ORD_A : OFF_ORD_E);
    int* __restrict__ rnk = (int*)ws + (side ? OFF_RANK_A : OFF_RANK_E);
    __shared__ unsigned char bgs[NPTS];
    __shared__ int cnts[8];
    int t = threadIdx.x;
    for (int i = t; i < NPTS; i += 1024) bgs[i] = (unsigned char)bg[i];
    __syncthreads();
    int w = t >> 6, lane = t & 63;
    if (w < 8) {
        int grp = w;
        int cnt = 0;
        for (int base = 0; base < NPTS; base += 64) {
            unsigned long long m = __ballot(bgs[base + lane] == grp);
            cnt += __popcll(m);
        }
        if (lane == 0) cnts[w] = cnt;
    }
    __syncthreads();
    if (w < 8) {
        int grp = w;
        int pos = 0;
        for (int g2 = 0; g2 < grp; g2++) pos += cnts[g2];
        for (int base = 0; base < NPTS; base += 64) {
            int hit = (bgs[base + lane] == grp);
            unsigned long long m = __ballot(hit);
            int pre = __popcll(m & ((1ull << lane) - 1ull));
            if (hit) {
                int slot = pos + pre;
                if (slot < NPTS) { ord[slot] = base + lane; rnk[base + lane] = slot; }
            }
            pos += __popcll(m);
        }
    }
}

// STREAMING gather-by-scatter, POINT-MAJOR P: one block per (f-half, b, side).
__global__ __launch_bounds__(512) void k_gather(const float* __restrict__ ex, const float* __restrict__ ac, float* ws) {
    int fh = blockIdx.x;
    int f = fh >> 1, half = fh & 1;
    int b = blockIdx.y, side = blockIdx.z;
    const int* __restrict__ rnk = (const int*)ws + (side ? OFF_RANK_A : OFF_RANK_E);
    const float4* __restrict__ src4 = (const float4*)((side ? ac : ex) + ((size_t)(b * FF + f) * NPTS) * CH);
    float* __restrict__ P = ws + OFF_MAT + (size_t)side * MATSZ;
    int t = threadIdx.x, w = t >> 6, lane = t & 63;
    float S[8][6];
#pragma unroll
    for (int gg = 0; gg < 8; gg++)
#pragma unroll
        for (int j = 0; j < 6; j++) S[gg][j] = 0.0f;

    float4 v0[2], v2[2], v3[2], v5[2], v6[2], v8[2];
    int4 rk[2];
#pragma unroll
    for (int pass = 0; pass < 2; pass++) {
        int quad = (half * 2 + pass) * 512 + t;   // 4 rows per quad
        const float4* pb = src4 + (size_t)quad * 11;
        v0[pass] = pb[0]; v2[pass] = pb[2]; v3[pass] = pb[3];
        v5[pass] = pb[5]; v6[pass] = pb[6]; v8[pass] = pb[8];
        rk[pass] = *(const int4*)(rnk + quad * 4);
    }
#pragma unroll
    for (int pass = 0; pass < 2; pass++) {
        float xs[4] = {v0[pass].x, v2[pass].w, v5[pass].z, v8[pass].y};
        float ys[4] = {v0[pass].y, v3[pass].x, v5[pass].w, v8[pass].z};
        float zs[4] = {v0[pass].z, v3[pass].y, v6[pass].x, v8[pass].w};
        int rr[4] = {rk[pass].x, rk[pass].y, rk[pass].z, rk[pass].w};
#pragma unroll
        for (int r = 0; r < 4; r++) {
            float x = xs[r], y = ys[r], z = zs[r];
            int g = rr[r] >> 10, pos = rr[r] & 1023;
            size_t mb = (((size_t)(g * 4 + b) * FF + f) * NG + pos) * 3;
            P[mb] = x; P[mb + 1] = y; P[mb + 2] = z;
#pragma unroll
            for (int gg = 0; gg < 8; gg++) {
                float hx = (g == gg) ? x : 0.0f;
                float hy = (g == gg) ? y : 0.0f;
                float hz = (g == gg) ? z : 0.0f;
                S[gg][0] += hx; S[gg][1] += hy; S[gg][2] += hz;
                S[gg][3] += hx * x; S[gg][4] += hy * y; S[gg][5] += hz * z;
            }
        }
    }
    __shared__ float accum[8][8][6];
#pragma unroll
    for (int gg = 0; gg < 8; gg++)
#pragma unroll
        for (int j = 0; j < 6; j++) {
            float s = S[gg][j];
#pragma unroll
            for (int off = 32; off; off >>= 1) s += __shfl_xor(s, off);
            if (lane == 0) accum[w][gg][j] = s;
        }
    __syncthreads();
    if (t < 48) {
        int g = t / 6, j = t % 6;
        float s = 0;
#pragma unroll
        for (int wv = 0; wv < 8; wv++) s += accum[wv][g][j];
        int gb = g * 4 + b;
        ws[OFF_MEANP + (((size_t)(side * NGB + gb) * FF + f) * 2 + half) * 6 + j] = s;
    }
}

// fused mean + 1/std finalize from (S1,S2) partials: one wave per (gb,side)
__global__ void k_statfin(float* ws) {
    int gb = blockIdx.x, side = blockIdx.y;
    int fl = threadIdx.x;   // 0..63 = f
    const float* mp = ws + OFF_MEANP + (((size_t)(side * NGB + gb) * FF + fl) * 2) * 6;
    float s0 = mp[0] + mp[6], s1 = mp[1] + mp[7], s2 = mp[2] + mp[8];
    float q0 = mp[3] + mp[9], q1 = mp[4] + mp[10], q2 = mp[5] + mp[11];
    float t0 = s0, t1 = s1, t2 = s2;
#pragma unroll
    for (int off = 32; off; off >>= 1) {
        t0 += __shfl_xor(t0, off); t1 += __shfl_xor(t1, off); t2 += __shfl_xor(t2, off);
    }
    float m0 = t0 / 65536.0f, m1 = t1 / 65536.0f, m2 = t2 / 65536.0f;
    float sumd = (s0 - 1024.0f * m0) + (s1 - 1024.0f * m1) + (s2 - 1024.0f * m2);
    float sumd2 = (q0 - 2.0f * m0 * s0 + 1024.0f * m0 * m0)
                + (q1 - 2.0f * m1 * s1 + 1024.0f * m1 * m1)
                + (q2 - 2.0f * m2 * s2 + 1024.0f * m2 * m2);
    float var = (sumd2 - sumd * sumd / 3072.0f) / 3071.0f;
    float* st = ws + (side ? OFF_STD_A : OFF_STD_E);
    st[gb * FF + fl] = 1.0f / sqrtf(fmaxf(var, 0.0f));
    if (fl == 0) {
        float* m = ws + (side ? OFF_MEAN_A : OFF_MEAN_E) + gb * 3;
        m[0] = m0; m[1] = m1; m[2] = m2;
    }
}

// transpose point-major P [f][pos][3] -> THREE bf16 mats [i][k] (P, V, NP)
__global__ void k_tobf3(float* ws) {
    int x = blockIdx.x;
    int it = x & 15, kt = x >> 4;
    int gb = blockIdx.y, side = blockIdx.z;
    int k0 = kt * 64, i0 = it * 64;
    int fstart = (k0 >= 3) ? (k0 - 3) / 3 : 0;
    int fend = (k0 + 63) / 3;
    int nf = fend - fstart + 1;     // 22/23/23
    const float* __restrict__ Pb = ws + OFF_MAT + (size_t)side * MATSZ + ((size_t)gb * FF) * NG * 3;
    unsigned short* bm = (unsigned short*)(ws + OFF_BMAT);
    const float* mean = ws + (side ? OFF_MEAN_A : OFF_MEAN_E) + gb * 3;
    const float* rst = ws + (side ? OFF_STD_A : OFF_STD_E) + gb * FF;
    float m0 = mean[0], m1 = mean[1], m2 = mean[2];
    __shared__ float tile[69][65];   // rows = krow = k - 3*fstart
    int t = threadIdx.x;
    int ii = t & 63, fq = t >> 6;
#pragma unroll
    for (int pass = 0; pass < 6; pass++) {
        int fl = pass * 4 + fq;
        if (fl < nf) {
            const float* p = Pb + (((size_t)(fstart + fl) * NG) + i0 + ii) * 3;
            tile[fl * 3 + 0][ii] = p[0];
            tile[fl * 3 + 1][ii] = p[1];
            tile[fl * 3 + 2][ii] = p[2];
        }
    }
    __syncthreads();
    int kk2 = t & 63, iq = t >> 6;
    int k = k0 + kk2;
    int c = k % 3, f = k / 3;
    int krow = k - fstart * 3;
    float mm = (c == 0) ? m0 : ((c == 1) ? m1 : m2);
    float rs = rst[f];
    size_t moff = ((size_t)side * NGB + gb) * (size_t)(NG * KF);
    size_t voff = ((size_t)(2 + side) * NGB + gb) * (size_t)(NG * KF);
    size_t noff = ((size_t)(4 + side) * NGB + gb) * (size_t)(NG * KF);
    float* npP = ws + OFF_NORMP + ((size_t)(side * NGB + gb) * 3 + kt) * NG;
    float* npV = ws + OFF_NORMP + ((size_t)((2 + side) * NGB + gb) * 3 + kt) * NG;
    float* npN = ws + OFF_NORMP + ((size_t)((4 + side) * NGB + gb) * 3 + kt) * NG;
#pragma unroll
    for (int rep = 0; rep < 16; rep++) {
        int i2 = iq + rep * 4;
        float p = tile[krow][i2];
        float vV = (k >= 3) ? (p - tile[krow - 3][i2]) : 0.0f;
        float vN = (p - mm) * rs;
        size_t ob = (size_t)(i0 + i2) * KF + k;
        bm[moff + ob] = f2bf(p);
        bm[voff + ob] = f2bf(vV);
        bm[noff + ob] = f2bf(vN);
        float nP = p * p, nV = vV * vV, nN = vN * vN;
#pragma unroll
        for (int off = 32; off; off >>= 1) {
            nP += __shfl_xor(nP, off); nV += __shfl_xor(nV, off); nN += __shfl_xor(nN, off);
        }
        if (kk2 == 0) { npP[i0 + i2] = nP; npV[i0 + i2] = nV; npN[i0 + i2] = nN; }
    }
}

__global__ void k_normfin(float* ws) {
    int mat = blockIdx.x, gb = blockIdx.y;
    const float* np = ws + OFF_NORMP + (size_t)(mat * NGB + gb) * 3 * NG;
    float* nr = ws + OFF_NORMS + ((size_t)mat * NGB + gb) * NG;
    for (int i = threadIdx.x; i < NG; i += 256)
        nr[i] = np[i] + np[NG + i] + np[2 * NG + i];
}

// MFMA distance GEMM: 128x128 tile, 4 waves (2x2), BK=64, swizzled LDS.
// Stores CLAMPED SQUARED distances as FP16 (monotone rounding).
__global__ __launch_bounds__(256) void k_mgemm(float* ws, int cs, unsigned long long dOff) {
    int bx = blockIdx.x, by = blockIdx.y;
    int bz = blockIdx.z; int gbl = bz / 3, m3 = bz % 3;
    int gb = cs + gbl;
    int eIdx = (m3 == 0) ? 0 : ((m3 == 1) ? 4 : 2);
    int aIdx = (m3 == 0) ? 1 : ((m3 == 1) ? 5 : 3);
    const unsigned short* bmat = (const unsigned short*)(ws + OFF_BMAT);
    const unsigned short* Eg = bmat + ((size_t)eIdx * NGB + gb) * (size_t)(NG * KF);
    const unsigned short* Ag = bmat + ((size_t)aIdx * NGB + gb) * (size_t)(NG * KF);
    const float* rnE = ws + OFF_NORMS + ((size_t)eIdx * NGB + gb) * NG;
    const float* cnA = ws + OFF_NORMS + ((size_t)aIdx * NGB + gb) * NG;
    unsigned short* D = (unsigned short*)(ws + dOff) + ((size_t)gbl * 3 + m3) * (size_t)(NG * NG);
    int i0 = by * 128, j0 = bx * 128;
    __shared__ unsigned short lE[128 * 64];
    __shared__ unsigned short lA[128 * 64];
    int tid = threadIdx.x;
    int wid = tid >> 6, lane = tid & 63;
    int wr = wid >> 1, wc = wid & 1;
    f32x4 acc[4][4];
#pragma unroll
    for (int m = 0; m < 4; m++)
#pragma unroll
        for (int n = 0; n < 4; n++) acc[m][n] = (f32x4){0.f, 0.f, 0.f, 0.f};

    int rr = lane >> 3, ss = lane & 7;
    for (int k0 = 0; k0 < KF; k0 += 64) {
        if (k0) __syncthreads();
#pragma unroll
        for (int q = 0; q < 4; q++) {
            int r0 = wid * 32 + q * 8;
            int r = r0 + rr;
            int c = ss ^ (r & 7);
            __builtin_amdgcn_global_load_lds(
                (const __attribute__((address_space(1))) void*)(Eg + (size_t)(i0 + r) * KF + k0 + c * 8),
                (__attribute__((address_space(3))) void*)&lE[r0 * 64], 16, 0, 0);
            __builtin_amdgcn_global_load_lds(
                (const __attribute__((address_space(1))) void*)(Ag + (size_t)(j0 + r) * KF + k0 + c * 8),
                (__attribute__((address_space(3))) void*)&lA[r0 * 64], 16, 0, 0);
        }
        asm volatile("s_waitcnt vmcnt(0)" ::: "memory");
        __syncthreads();
#pragma unroll
        for (int ks = 0; ks < 2; ks++) {
            bf16x8 af[4], bfr[4];
            int kb = ks * 64 + (lane >> 4) * 16;
#pragma unroll
            for (int m = 0; m < 4; m++) {
                int arow = wr * 64 + m * 16 + (lane & 15);
                af[m] = *(const bf16x8*)((const char*)lE + arow * 128 + (kb ^ ((arow & 7) << 4)));
            }
#pragma unroll
            for (int n = 0; n < 4; n++) {
                int brow = wc * 64 + n * 16 + (lane & 15);
                bfr[n] = *(const bf16x8*)((const char*)lA + brow * 128 + (kb ^ ((brow & 7) << 4)));
            }
#pragma unroll
            for (int m = 0; m < 4; m++)
#pragma unroll
                for (int n = 0; n < 4; n++)
                    acc[m][n] = __builtin_amdgcn_mfma_f32_16x16x32_bf16(af[m], bfr[n], acc[m][n], 0, 0, 0);
        }
    }

    int colbase = j0 + wc * 64 + (lane & 15);
    int rowbase = i0 + wr * 64 + ((lane >> 4) << 2);
    float cn[4];
#pragma unroll
    for (int n = 0; n < 4; n++) cn[n] = cnA[colbase + n * 16];
#pragma unroll
    for (int m = 0; m < 4; m++) {
        int rb = rowbase + m * 16;
#pragma unroll
        for (int r = 0; r < 4; r++) {
            float rn = rnE[rb + r];
#pragma unroll
            for (int n = 0; n < 4; n++) {
                float d = rn + cn[n] - 2.0f * acc[m][n][r];
                D[(size_t)(rb + r) * NG + colbase + n * 16] = f2h(fmaxf(d, 1e-12f));
            }
        }
    }
}

// ---- fallback path (small ws): column-major gather + fp32 derive/norms/gemm ----
__global__ __launch_bounds__(512) void k_gather_cols(const float* __restrict__ ex, const float* __restrict__ ac, float* ws) {
    int fh = blockIdx.x;
    int f = fh >> 1, half = fh & 1;
    int b = blockIdx.y, side = blockIdx.z;
    const int* __restrict__ rnk = (const int*)ws + (side ? OFF_RANK_A : OFF_RANK_E);
    const float4* __restrict__ src4 = (const float4*)((side ? ac : ex) + ((size_t)(b * FF + f) * NPTS) * CH);
    float* __restrict__ P = ws + OFF_MAT + (size_t)side * MATSZ;
    int t = threadIdx.x, w = t >> 6, lane = t & 63;
    float S[8][6];
#pragma unroll
    for (int gg = 0; gg < 8; gg++)
#pragma unroll
        for (int j = 0; j < 6; j++) S[gg][j] = 0.0f;
#pragma unroll
    for (int pass = 0; pass < 2; pass++) {
        int quad = (half * 2 + pass) * 512 + t;
        int n0 = quad * 4;
        const float4* pb = src4 + (size_t)quad * 11;
        float4 v0 = pb[0], v2 = pb[2], v3 = pb[3], v5 = pb[5], v6 = pb[6], v8 = pb[8];
        int4 rk = *(const int4*)(rnk + n0);
        float xs[4] = {v0.x, v2.w, v5.z, v8.y};
        float ys[4] = {v0.y, v3.x, v5.w, v8.z};
        float zs[4] = {v0.z, v3.y, v6.x, v8.w};
        int rr[4] = {rk.x, rk.y, rk.z, rk.w};
#pragma unroll
        for (int r = 0; r < 4; r++) {
            float x = xs[r], y = ys[r], z = zs[r];
            int g = rr[r] >> 10, pos = rr[r] & 1023;
            size_t mb = ((size_t)((g * 4 + b) * KF + f * 3)) * NG + pos;
            P[mb] = x; P[mb + NG] = y; P[mb + 2 * NG] = z;
#pragma unroll
            for (int gg = 0; gg < 8; gg++) {
                float hx = (g == gg) ? x : 0.0f;
                float hy = (g == gg) ? y : 0.0f;
                float hz = (g == gg) ? z : 0.0f;
                S[gg][0] += hx; S[gg][1] += hy; S[gg][2] += hz;
                S[gg][3] += hx * x; S[gg][4] += hy * y; S[gg][5] += hz * z;
            }
        }
    }
    __shared__ float accum[8][8][6];
#pragma unroll
    for (int gg = 0; gg < 8; gg++)
#pragma unroll
        for (int j = 0; j < 6; j++) {
            float s = S[gg][j];
#pragma unroll
            for (int off = 32; off; off >>= 1) s += __shfl_xor(s, off);
            if (lane == 0) accum[w][gg][j] = s;
        }
    __syncthreads();
    if (t < 48) {
        int g = t / 6, j = t % 6;
        float s = 0;
#pragma unroll
        for (int wv = 0; wv < 8; wv++) s += accum[wv][g][j];
        int gb = g * 4 + b;
        ws[OFF_MEANP + (((size_t)(side * NGB + gb) * FF + f) * 2 + half) * 6 + j] = s;
    }
}

__global__ void k_derive(float* ws) {
    int k = blockIdx.x, gb = blockIdx.y;
    int f = k / 3, c = k % 3;
    for (int side = 0; side < 2; side++) {
        const float* P = ws + OFF_MAT + (size_t)side * MATSZ;
        float* V = ws + OFF_MAT + (size_t)(2 + side) * MATSZ;
        float* NP = ws + OFF_MAT + (size_t)(4 + side) * MATSZ;
        const float* mean = ws + (side ? OFF_MEAN_A : OFF_MEAN_E) + gb * 3;
        const float* rst = ws + (side ? OFF_STD_A : OFF_STD_E) + gb * FF;
        float mm = mean[c];
        float rs = rst[f];
        size_t base = ((size_t)gb * KF + k) * NG;
        for (int i = threadIdx.x; i < NG; i += 256) {
            float p = P[base + i];
            V[base + i] = f ? (p - P[base - 3 * NG + i]) : 0.0f;
            NP[base + i] = (p - mm) * rs;
        }
    }
}

__global__ void k_norms(float* ws) {
    int mat = blockIdx.x, gb = blockIdx.y;
    const float* M = ws + OFF_MAT + (size_t)mat * MATSZ + (size_t)gb * KF * NG;
    float* nr = ws + OFF_NORMS + ((size_t)mat * NGB + gb) * NG;
    for (int i = threadIdx.x; i < NG; i += 256) {
        float s = 0;
        for (int k = 0; k < KF; k++) { float v = M[(size_t)k * NG + i]; s += v * v; }
        nr[i] = s;
    }
}

__global__ __launch_bounds__(256) void k_gemm(float* ws, int cs) {
    int bx = blockIdx.x, by = blockIdx.y;
    int bz = blockIdx.z; int gbl = bz / 3, m = bz % 3;
    int gb = cs + gbl;
    int eIdx = (m == 0) ? 0 : ((m == 1) ? 4 : 2);
    int aIdx = (m == 0) ? 1 : ((m == 1) ? 5 : 3);
    const float* E = ws + OFF_MAT + (size_t)eIdx * MATSZ + (size_t)gb * KF * NG;
    const float* A = ws + OFF_MAT + (size_t)aIdx * MATSZ + (size_t)gb * KF * NG;
    const float* rnE = ws + OFF_NORMS + ((size_t)eIdx * NGB + gb) * NG;
    const float* cnA = ws + OFF_NORMS + ((size_t)aIdx * NGB + gb) * NG;
    unsigned short* D = (unsigned short*)(ws + OFF_D) + ((size_t)gbl * 3 + m) * (size_t)(NG * NG);
    int i0 = by * 128, j0 = bx * 128;
    __shared__ float4 Et[8][32], At[8][32];
    int tx = threadIdx.x, ty = threadIdx.y;
    int tid = ty * 16 + tx;
    float acc[2][2][4][4] = {};
    for (int k0 = 0; k0 < KF; k0 += 8) {
        {
            int kk = tid >> 5, i4 = tid & 31;
            Et[kk][i4] = *(const float4*)&E[(size_t)(k0 + kk) * NG + i0 + i4 * 4];
            At[kk][i4] = *(const float4*)&A[(size_t)(k0 + kk) * NG + j0 + i4 * 4];
        }
        __syncthreads();
#pragma unroll
        for (int kk = 0; kk < 8; kk++) {
            float4 e0 = Et[kk][ty], e1 = Et[kk][16 + ty];
            float4 a0 = At[kk][tx], a1 = At[kk][16 + tx];
            float er[2][4] = {{e0.x, e0.y, e0.z, e0.w}, {e1.x, e1.y, e1.z, e1.w}};
            float ar[2][4] = {{a0.x, a0.y, a0.z, a0.w}, {a1.x, a1.y, a1.z, a1.w}};
#pragma unroll
            for (int p = 0; p < 2; p++)
#pragma unroll
                for (int q = 0; q < 2; q++)
#pragma unroll
                    for (int r = 0; r < 4; r++)
#pragma unroll
                        for (int cc = 0; cc < 4; cc++)
                            acc[p][q][r][cc] += er[p][r] * ar[q][cc];
        }
        __syncthreads();
    }
    float rn[2][4], cn[2][4];
#pragma unroll
    for (int p = 0; p < 2; p++)
#pragma unroll
        for (int r = 0; r < 4; r++) rn[p][r] = rnE[i0 + p * 64 + ty * 4 + r];
#pragma unroll
    for (int q = 0; q < 2; q++)
#pragma unroll
        for (int cc = 0; cc < 4; cc++) cn[q][cc] = cnA[j0 + q * 64 + tx * 4 + cc];
#pragma unroll
    for (int p = 0; p < 2; p++)
#pragma unroll
        for (int r = 0; r < 4; r++) {
            int gi = i0 + p * 64 + ty * 4 + r;
#pragma unroll
            for (int q = 0; q < 2; q++)
#pragma unroll
                for (int cc = 0; cc < 4; cc++) {
                    float d = fmaxf(rn[p][r] + cn[q][cc] - 2.0f * acc[p][q][r][cc], 1e-12f);
                    D[(size_t)gi * NG + j0 + q * 64 + tx * 4 + cc] = f2h(d);
                }
        }
}

// ---------------------------------------------------------------------------
// per-row top-16 on FP16 squared distances via bound -> compact -> bitonic.
// Loads: 2x uint4 per list per lane. value slot vq (0..15):
//   col = (vq<8) ? 8*lane + vq : 512 + 8*lane + (vq-8)
// ---------------------------------------------------------------------------
__global__ void k_select(float* ws, int cs, unsigned long long dOff) {
    int gbl = blockIdx.y; int gb = cs + gbl;
    int w = threadIdx.x >> 6, lane = threadIdx.x & 63;
    int row = blockIdx.x * 4 + w;
    const unsigned short* Db = (const unsigned short*)(ws + dOff) + (size_t)gbl * 3 * (size_t)(NG * NG);
    const uint4* dg4 = (const uint4*)(Db + (size_t)row * NG);
    const uint4* dn4 = (const uint4*)(Db + (size_t)(NG * NG) + (size_t)row * NG);
    const uint4* dv4 = (const uint4*)(Db + (size_t)2 * (NG * NG) + (size_t)row * NG);
    uint4 ga = dg4[lane], gbq = dg4[64 + lane];
    uint4 na = dn4[lane], nb = dn4[64 + lane];
    uint4 va = dv4[lane], vb = dv4[64 + lane];
    unsigned ug[8] = {ga.x, ga.y, ga.z, ga.w, gbq.x, gbq.y, gbq.z, gbq.w};
    unsigned un[8] = {na.x, na.y, na.z, na.w, nb.x, nb.y, nb.z, nb.w};
    unsigned uv[8] = {va.x, va.y, va.z, va.w, vb.x, vb.y, vb.z, vb.w};
    float dgv[16], dnv[16], dvv[16];
#pragma unroll
    for (int q = 0; q < 8; q++) {
        dgv[2 * q] = h2f(ug[q]); dgv[2 * q + 1] = h2f(ug[q] >> 16);
        dnv[2 * q] = h2f(un[q]); dnv[2 * q + 1] = h2f(un[q] >> 16);
        dvv[2 * q] = h2f(uv[q]); dvv[2 * q + 1] = h2f(uv[q] >> 16);
    }
    __shared__ float sKey[4][64];
    __shared__ float sPay[4][64];
    __shared__ int   sCol[4][64];
    unsigned long long ltm = (1ull << lane) - 1ull;
    float sg = 0, sv = 0, sn = 0;
    int colb = lane * 8;

    // ============ list A: dg (payload dv, tie-break col) ============
    {
        float lm = dgv[0];
#pragma unroll
        for (int q = 1; q < 16; q++) lm = fminf(lm, dgv[q]);
#pragma unroll
        for (int k2 = 2; k2 <= 64; k2 <<= 1)
#pragma unroll
            for (int j = k2 >> 1; j; j >>= 1) {
                float o = __shfl_xor(lm, j);
                bool takeMin = (((lane & j) == 0) == ((lane & k2) == 0));
                lm = takeMin ? fminf(lm, o) : fmaxf(lm, o);
            }
        float tau = __shfl(lm, 15);
        int cnt = 0;
#pragma unroll
        for (int q = 0; q < 16; q++) cnt += (int)__popcll(__ballot(dgv[q] <= tau));
        if (cnt <= 64) {
            int base = 0;
#pragma unroll
            for (int vq = 0; vq < 16; vq++) {
                bool c = (dgv[vq] <= tau);
                unsigned long long bal = __ballot(c);
                if (c) {
                    int slot = base + (int)__popcll(bal & ltm);
                    sKey[w][slot] = dgv[vq]; sPay[w][slot] = dvv[vq];
                    sCol[w][slot] = (vq < 8) ? (colb + vq) : (512 + colb + vq - 8);
                }
                base += (int)__popcll(bal);
            }
            asm volatile("s_waitcnt lgkmcnt(0)" ::: "memory");
            float key = (lane < cnt) ? sKey[w][lane] : 3.4e38f;
            float pay = (lane < cnt) ? sPay[w][lane] : 0.0f;
            int   col = (lane < cnt) ? sCol[w][lane] : 0x7fffffff;
#pragma unroll
            for (int k2 = 2; k2 <= 64; k2 <<= 1)
#pragma unroll
                for (int j = k2 >> 1; j; j >>= 1) {
                    float ok = __shfl_xor(key, j);
                    float op = __shfl_xor(pay, j);
                    int   oc = __shfl_xor(col, j);
                    bool mineSmaller = (key < ok) || (key == ok && col < oc);
                    bool wantSmall = (((lane & j) == 0) == ((lane & k2) == 0));
                    if (mineSmaller != wantSmall) { key = ok; pay = op; col = oc; }
                }
            float a = (lane < 16) ? sqrtf(key) : 0.0f;
            float b = (lane < 16) ? sqrtf(pay) : 0.0f;
#pragma unroll
            for (int off = 32; off; off >>= 1) { a += __shfl_xor(a, off); b += __shfl_xor(b, off); }
            sg = a; sv = b;
        } else {
            for (int it = 0; it < KNN; it++) {
                float best = 3.4e38f; int bc = 0x7fffffff;
#pragma unroll
                for (int vq = 0; vq < 16; vq++) {
                    float v = dgv[vq];
                    int c = (vq < 8) ? (colb + vq) : (512 + colb + vq - 8);
                    if (v < best) { best = v; bc = c; }
                }
#pragma unroll
                for (int off = 32; off; off >>= 1) {
                    float ov = __shfl_xor(best, off); int oc = __shfl_xor(bc, off);
                    if (ov < best || (ov == best && oc < bc)) { best = ov; bc = oc; }
                }
                sg += sqrtf(best);
                int bl = ((bc & 511) >> 3);
                int bq = (bc & 7) + ((bc >= 512) ? 8 : 0);
                float t = 0;
#pragma unroll
                for (int vq = 0; vq < 16; vq++) if (vq == bq) t = dvv[vq];
                t = __shfl(t, bl); sv += sqrtf(t);
                if (lane == bl) {
#pragma unroll
                    for (int vq = 0; vq < 16; vq++) if (vq == bq) dgv[vq] = 3.4e38f;
                }
            }
        }
    }

    // ============ list B: dn (values only) ============
    {
        float lm = dnv[0];
#pragma unroll
        for (int q = 1; q < 16; q++) lm = fminf(lm, dnv[q]);
#pragma unroll
        for (int k2 = 2; k2 <= 64; k2 <<= 1)
#pragma unroll
            for (int j = k2 >> 1; j; j >>= 1) {
                float o = __shfl_xor(lm, j);
                bool takeMin = (((lane & j) == 0) == ((lane & k2) == 0));
                lm = takeMin ? fminf(lm, o) : fmaxf(lm, o);
            }
        float tau = __shfl(lm, 15);
        int cnt = 0;
#pragma unroll
        for (int q = 0; q < 16; q++) cnt += (int)__popcll(__ballot(dnv[q] <= tau));
        if (cnt <= 64) {
            int base = 0;
#pragma unroll
            for (int vq = 0; vq < 16; vq++) {
                bool c = (dnv[vq] <= tau);
                unsigned long long bal = __ballot(c);
                if (c) {
                    int slot = base + (int)__popcll(bal & ltm);
                    sKey[w][slot] = dnv[vq];
                }
                base += (int)__popcll(bal);
            }
            asm volatile("s_waitcnt lgkmcnt(0)" ::: "memory");
            float key = (lane < cnt) ? sKey[w][lane] : 3.4e38f;
#pragma unroll
            for (int k2 = 2; k2 <= 64; k2 <<= 1)
#pragma unroll
                for (int j = k2 >> 1; j; j >>= 1) {
                    float o = __shfl_xor(key, j);
                    bool takeMin = (((lane & j) == 0) == ((lane & k2) == 0));
                    key = takeMin ? fminf(key, o) : fmaxf(key, o);
                }
            float a = (lane < 16) ? sqrtf(key) : 0.0f;
#pragma unroll
            for (int off = 32; off; off >>= 1) a += __shfl_xor(a, off);
            sn = a;
        } else {
            for (int it = 0; it < KNN; it++) {
                float best = 3.4e38f; int bc = 0x7fffffff;
#pragma unroll
                for (int vq = 0; vq < 16; vq++) {
                    float v = dnv[vq];
                    int c = (vq < 8) ? (colb + vq) : (512 + colb + vq - 8);
                    if (v < best) { best = v; bc = c; }
                }
#pragma unroll
                for (int off = 32; off; off >>= 1) {
                    float ov = __shfl_xor(best, off); int oc = __shfl_xor(bc, off);
                    if (ov < best || (ov == best && oc < bc)) { best = ov; bc = oc; }
                }
                sn += sqrtf(best);
                int bl = ((bc & 511) >> 3);
                int bq = (bc & 7) + ((bc >= 512) ? 8 : 0);
                if (lane == bl) {
#pragma unroll
                    for (int vq = 0; vq < 16; vq++) if (vq == bq) dnv[vq] = 3.4e38f;
                }
            }
        }
    }

    __shared__ float ssum[4][3];
    if (lane == 0) { ssum[w][0] = sg; ssum[w][1] = sn; ssum[w][2] = sv; }
    __syncthreads();
    if (threadIdx.x == 0) {
        float* part = ws + OFF_PART + ((size_t)gb * 256 + blockIdx.x) * 3;
        part[0] = ssum[0][0] + ssum[1][0] + ssum[2][0] + ssum[3][0];
        part[1] = ssum[0][1] + ssum[1][1] + ssum[2][1] + ssum[3][1];
        part[2] = ssum[0][2] + ssum[1][2] + ssum[2][2] + ssum[3][2];
    }
}

__global__ void k_reduce(float* ws, float* out, int n) {
    double s[3] = {0, 0, 0};
    for (int idx = threadIdx.x; idx < n; idx += 256) {
        const float* p = ws + OFF_PART + (size_t)idx * 3;
        s[0] += p[0]; s[1] += p[1]; s[2] += p[2];
    }
    __shared__ double red[256];
    for (int m = 0; m < 3; m++) {
        red[threadIdx.x] = s[m]; __syncthreads();
        for (int off = 128; off; off >>= 1) { if (threadIdx.x < off) red[threadIdx.x] += red[threadIdx.x + off]; __syncthreads(); }
        if (threadIdx.x == 0) out[m] = (float)(red[0] / 524288.0 / 8.0);
        __syncthreads();
    }
}

extern "C" void kernel_launch(void* const* d_in, const int* in_sizes, int n_in,
                              void* d_out, int out_size, void* d_ws, size_t ws_size,
                              hipStream_t stream) {
    const float* ex = (const float*)d_in[0];
    const float* ac = (const float*)d_in[1];
    float* ws = (float*)d_ws;
    float* out = (float*)d_out;

    hipLaunchKernelGGL(k_bg, dim3(64), dim3(256), 0, stream, ex, ac, ws);
    hipLaunchKernelGGL(k_order, dim3(2), dim3(1024), 0, stream, ws);

    size_t ws_floats = ws_size / 4;
    bool fast = ws_floats >= (size_t)FAST_END;

    if (fast) {
        hipLaunchKernelGGL(k_gather, dim3(128, BB, 2), dim3(512), 0, stream, ex, ac, ws);
        hipLaunchKernelGGL(k_statfin, dim3(NGB, 2), dim3(64), 0, stream, ws);
        hipLaunchKernelGGL(k_tobf3, dim3(48, NGB, 2), dim3(256), 0, stream, ws);
        hipLaunchKernelGGL(k_normfin, dim3(6, NGB), dim3(256), 0, stream, ws);
        int gbc = 16;  // fp16 D overlays the dead fp32 P region after k_tobf3
        for (int cs = 0; cs < NGB; cs += gbc) {
            int take = (NGB - cs < gbc) ? (NGB - cs) : gbc;
            hipLaunchKernelGGL(k_mgemm, dim3(8, 8, take * 3), dim3(256), 0, stream, ws, cs, (unsigned long long)OFF_MAT);
            hipLaunchKernelGGL(k_select, dim3(256, take), dim3(256), 0, stream, ws, cs, (unsigned long long)OFF_MAT);
        }
        hipLaunchKernelGGL(k_reduce, dim3(1), dim3(256), 0, stream, ws, out, 8192);
    } else {
        hipLaunchKernelGGL(k_gather_cols, dim3(128, BB, 2), dim3(512), 0, stream, ex, ac, ws);
        hipLaunchKernelGGL(k_statfin, dim3(NGB, 2), dim3(64), 0, stream, ws);
        hipLaunchKernelGGL(k_derive, dim3(KF, NGB), dim3(256), 0, stream, ws);
        hipLaunchKernelGGL(k_norms, dim3(6, NGB), dim3(256), 0, stream, ws);
        size_t dcap = (ws_floats > (size_t)OFF_D) ? (ws_floats - (size_t)OFF_D) : 0;
        int gbc = (int)(dcap / (size_t)D_FLOATS_PER_GB);
        if (gbc < 1) gbc = 1;
        if (gbc > 32) gbc = 32;
        for (int cs = 0; cs < NGB; cs += gbc) {
            int take = (NGB - cs < gbc) ? (NGB - cs) : gbc;
            hipLaunchKernelGGL(k_gemm, dim3(8, 8, take * 3), dim3(16, 16), 0, stream, ws, cs);
            hipLaunchKernelGGL(k_select, dim3(256, take), dim3(256), 0, stream, ws, cs, (unsigned long long)OFF_D);
        }
        hipLaunchKernelGGL(k_reduce, dim3(1), dim3(256), 0, stream, ws, out, 8192);
    }
}